// Round 2
// baseline (418.513 us; speedup 1.0000x reference)
//
#include <hip/hip_runtime.h>
#include <hip/hip_bf16.h>
#include <math.h>
#include <type_traits>

// Problem: B=2, LQ=LM=2048, D=1024, H=16, DH=64.
// Device I/O is FLOAT32 (per reference); bf16 internal compute (MFMA) allowed
// by the loose threshold. Pipeline: QKV proj GEMMs -> flash attention -> out GEMM.

typedef __bf16 bf16;
typedef __bf16 bf16x4 __attribute__((ext_vector_type(4)));
typedef __bf16 bf16x8 __attribute__((ext_vector_type(8)));
typedef float f32x4 __attribute__((ext_vector_type(4)));

#define MFMA16(a, b, c) __builtin_amdgcn_mfma_f32_16x16x32_bf16((a), (b), (c), 0, 0, 0)

// ---------------------------------------------------------------------------
// GEMM: out = (A[M,1024] @ W[1024,1024] + bias) * alpha
// TA: float (global f32, cvt->bf16 in staging) or bf16 (workspace).
// TO: bf16 (workspace) or float (final output).
// mode 0: out[m][n] row-major. mode 1: per-batch transposed out[b][n][t],
//         m = b*2048+t (V^T layout for attention).
// BM=128, BN=128, BK=64; 256 threads = 4 waves (2x2), 64x64 out per wave.
// ---------------------------------------------------------------------------
template <typename TA, typename TO>
__global__ __launch_bounds__(256) void gemm_kernel(
    const TA* __restrict__ A, const float* __restrict__ W,
    const float* __restrict__ bias, TO* __restrict__ out,
    float alpha, int mode)
{
    __shared__ bf16 As[128][72];    // +8 pad
    __shared__ bf16 Ws[64][136];    // +8 pad

    const int tid = threadIdx.x;
    const int n0 = blockIdx.x * 128;
    const int m0 = blockIdx.y * 128;
    const int w = tid >> 6, lane = tid & 63;
    const int lr = lane & 15, lg = lane >> 4;
    const int wm = (w >> 1) * 64, wn = (w & 1) * 64;

    f32x4 acc[4][4] = {};

    for (int kt = 0; kt < 1024; kt += 64) {
        // stage A tile 128x64 -> bf16 LDS
        if constexpr (std::is_same<TA, float>::value) {
            #pragma unroll
            for (int p = 0; p < 8; ++p) {
                int c = p * 256 + tid;            // 2048 float4 chunks
                int row = c >> 4, c4 = (c & 15) * 4;
                float4 f = *(const float4*)&A[(m0 + row) * 1024 + kt + c4];
                bf16x4 h;
                h[0] = (bf16)f.x; h[1] = (bf16)f.y; h[2] = (bf16)f.z; h[3] = (bf16)f.w;
                *(bf16x4*)&As[row][c4] = h;
            }
        } else {
            #pragma unroll
            for (int p = 0; p < 4; ++p) {
                int c = p * 256 + tid;            // 1024 bf16x8 chunks
                int row = c >> 3, c8 = (c & 7) * 8;
                *(uint4*)&As[row][c8] = *(const uint4*)&A[(m0 + row) * 1024 + kt + c8];
            }
        }
        // stage W tile 64x128 (f32 global) -> bf16 LDS
        #pragma unroll
        for (int p = 0; p < 8; ++p) {
            int c = p * 256 + tid;                // 2048 float4 chunks
            int krow = c >> 5, c4 = (c & 31) * 4;
            float4 f = *(const float4*)&W[(kt + krow) * 1024 + n0 + c4];
            bf16x4 h;
            h[0] = (bf16)f.x; h[1] = (bf16)f.y; h[2] = (bf16)f.z; h[3] = (bf16)f.w;
            *(bf16x4*)&Ws[krow][c4] = h;
        }
        __syncthreads();

        #pragma unroll
        for (int ks = 0; ks < 2; ++ks) {
            const int kb = ks * 32 + lg * 8;
            bf16x8 af[4];
            #pragma unroll
            for (int mt = 0; mt < 4; ++mt)
                af[mt] = *(const bf16x8*)&As[wm + mt * 16 + lr][kb];
            #pragma unroll
            for (int nt = 0; nt < 4; ++nt) {
                bf16x8 bfv;
                #pragma unroll
                for (int j = 0; j < 8; ++j)
                    bfv[j] = Ws[kb + j][wn + nt * 16 + lr];
                #pragma unroll
                for (int mt = 0; mt < 4; ++mt)
                    acc[mt][nt] = MFMA16(af[mt], bfv, acc[mt][nt]);
            }
        }
        __syncthreads();
    }

    // epilogue: D layout col=lane&15, row=(lane>>4)*4+i
    #pragma unroll
    for (int nt = 0; nt < 4; ++nt) {
        const int n = n0 + wn + nt * 16 + lr;
        const float bv = bias[n];
        #pragma unroll
        for (int mt = 0; mt < 4; ++mt) {
            #pragma unroll
            for (int i = 0; i < 4; ++i) {
                const int m = m0 + wm + mt * 16 + lg * 4 + i;
                const float v = (acc[mt][nt][i] + bv) * alpha;
                if (mode == 0) {
                    out[m * 1024 + n] = (TO)v;
                } else {
                    const int b = m >> 11, t = m & 2047;
                    out[((b << 10) + n) * 2048 + t] = (TO)v;
                }
            }
        }
    }
}

// ---------------------------------------------------------------------------
// Flash attention. Grid (LQ/64, H, B), 256 threads = 4 waves x 16 q-rows.
// Q[B*LQ,1024](bf16), K[B*LM,1024](bf16), Vt[B][1024][2048](bf16),
// mbias[B,LM](f32). Online softmax in fp32.
// ---------------------------------------------------------------------------
__global__ __launch_bounds__(256) void attn_kernel(
    const bf16* __restrict__ Q, const bf16* __restrict__ K,
    const bf16* __restrict__ Vt, const float* __restrict__ mbias,
    bf16* __restrict__ Oout)
{
    __shared__ bf16 Ps[4][16][72];   // per-wave private P tile (16 q x 64 keys)

    const int tid = threadIdx.x;
    const int w = tid >> 6, lane = tid & 63;
    const int lr = lane & 15, lg = lane >> 4;
    const int qt = blockIdx.x, h = blockIdx.y, b = blockIdx.z;
    const int qrow = qt * 64 + w * 16;

    // Q fragments (A-operand), hoisted: row=lr, k = ks*32 + 8*lg + j
    const long qoff = (long)(b * 2048 + qrow + lr) * 1024 + h * 64;
    bf16x8 qf[2];
    qf[0] = *(const bf16x8*)&Q[qoff + lg * 8];
    qf[1] = *(const bf16x8*)&Q[qoff + 32 + lg * 8];

    const bf16* Kb = K + (long)b * 2048 * 1024 + h * 64;
    const bf16* Vb = Vt + ((long)b * 1024 + h * 64) * 2048;
    const float* biasb = mbias + b * 2048;

    float m_run[4], l_run[4];
    f32x4 of[4] = {};
    #pragma unroll
    for (int i = 0; i < 4; ++i) { m_run[i] = -INFINITY; l_run[i] = 0.f; }

    for (int key0 = 0; key0 < 2048; key0 += 64) {
        // ---- S = Q K^T : S[16 q x 64 keys] in 4 frags ----
        f32x4 s[4] = {};
        #pragma unroll
        for (int ks = 0; ks < 2; ++ks) {
            const int kb = ks * 32 + lg * 8;
            #pragma unroll
            for (int nt = 0; nt < 4; ++nt) {
                bf16x8 kf = *(const bf16x8*)&Kb[(long)(key0 + nt * 16 + lr) * 1024 + kb];
                s[nt] = MFMA16(qf[ks], kf, s[nt]);
            }
        }
        // ---- + memory_bias, row max (row r=lg*4+i lives on the 16 lanes of lg) ----
        float rowm[4] = {-INFINITY, -INFINITY, -INFINITY, -INFINITY};
        #pragma unroll
        for (int nt = 0; nt < 4; ++nt) {
            const float bv = biasb[key0 + nt * 16 + lr];
            #pragma unroll
            for (int i = 0; i < 4; ++i) {
                s[nt][i] += bv;
                rowm[i] = fmaxf(rowm[i], s[nt][i]);
            }
        }
        #pragma unroll
        for (int off = 1; off < 16; off <<= 1)
            #pragma unroll
            for (int i = 0; i < 4; ++i)
                rowm[i] = fmaxf(rowm[i], __shfl_xor(rowm[i], off, 64));

        // ---- online softmax update ----
        float al[4];
        #pragma unroll
        for (int i = 0; i < 4; ++i) {
            const float mnew = fmaxf(m_run[i], rowm[i]);
            al[i] = expf(m_run[i] - mnew);
            m_run[i] = mnew;
            l_run[i] *= al[i];
            #pragma unroll
            for (int dt = 0; dt < 4; ++dt) of[dt][i] *= al[i];
        }
        float rsum[4] = {0.f, 0.f, 0.f, 0.f};
        #pragma unroll
        for (int nt = 0; nt < 4; ++nt)
            #pragma unroll
            for (int i = 0; i < 4; ++i) {
                const float p = expf(s[nt][i] - m_run[i]);
                rsum[i] += p;
                Ps[w][lg * 4 + i][nt * 16 + lr] = (bf16)p;
            }
        #pragma unroll
        for (int off = 1; off < 16; off <<= 1)
            #pragma unroll
            for (int i = 0; i < 4; ++i)
                rsum[i] += __shfl_xor(rsum[i], off, 64);
        #pragma unroll
        for (int i = 0; i < 4; ++i) l_run[i] += rsum[i];

        __syncthreads();   // P writes visible

        // ---- O += P V : A-frag from Ps, B-frag contiguous from Vt ----
        #pragma unroll
        for (int ks = 0; ks < 2; ++ks) {
            bf16x8 pa = *(const bf16x8*)&Ps[w][lr][ks * 32 + lg * 8];
            #pragma unroll
            for (int dt = 0; dt < 4; ++dt) {
                bf16x8 vf = *(const bf16x8*)&Vb[(long)(dt * 16 + lr) * 2048 + key0 + ks * 32 + lg * 8];
                of[dt] = MFMA16(pa, vf, of[dt]);
            }
        }
        __syncthreads();
    }

    // ---- finalize: O / l, store bf16 [B*LQ, 1024] ----
    const long obase = (long)(b * 2048 + qrow + lg * 4) * 1024 + h * 64;
    #pragma unroll
    for (int dt = 0; dt < 4; ++dt)
        #pragma unroll
        for (int i = 0; i < 4; ++i) {
            const float v = of[dt][i] / l_run[i];
            Oout[obase + (long)i * 1024 + dt * 16 + lr] = (bf16)v;
        }
}

// ---------------------------------------------------------------------------
extern "C" void kernel_launch(void* const* d_in, const int* in_sizes, int n_in,
                              void* d_out, int out_size, void* d_ws, size_t ws_size,
                              hipStream_t stream) {
    const float* query  = (const float*)d_in[0];
    const float* memory = (const float*)d_in[1];
    const float* mbias  = (const float*)d_in[2];
    const float* Wq = (const float*)d_in[3];
    const float* bq = (const float*)d_in[4];
    const float* Wk = (const float*)d_in[5];
    const float* bk = (const float*)d_in[6];
    const float* Wv = (const float*)d_in[7];
    const float* bv = (const float*)d_in[8];
    const float* Wo = (const float*)d_in[9];
    const float* bo = (const float*)d_in[10];
    float* out = (float*)d_out;

    const size_t SZ = 4096ull * 1024ull * sizeof(bf16);   // 8 MiB per buffer
    char* ws = (char*)d_ws;
    bf16* Qp  = (bf16*)(ws);
    bf16* Kp  = (bf16*)(ws + SZ);
    bf16* Vtp = (bf16*)(ws + 2 * SZ);
    bf16* Ap  = (bf16*)(ws + 3 * SZ);

    dim3 blk(256);
    dim3 gg(8, 32);          // N/128, M/128
    gemm_kernel<float, bf16><<<gg, blk, 0, stream>>>(query,  Wq, bq, Qp,  0.125f, 0);
    gemm_kernel<float, bf16><<<gg, blk, 0, stream>>>(memory, Wk, bk, Kp,  1.0f,   0);
    gemm_kernel<float, bf16><<<gg, blk, 0, stream>>>(memory, Wv, bv, Vtp, 1.0f,   1);
    attn_kernel<<<dim3(32, 16, 2), blk, 0, stream>>>(Qp, Kp, Vtp, mbias, Ap);
    gemm_kernel<bf16, float><<<gg, blk, 0, stream>>>(Ap, Wo, bo, out, 1.0f, 0);
}

// Round 4
// 354.615 us; speedup vs baseline: 1.1802x; 1.1802x over previous
//
#include <hip/hip_runtime.h>
#include <hip/hip_bf16.h>
#include <math.h>
#include <type_traits>

// B=2, LQ=LM=2048, D=1024, H=16, DH=64. f32 I/O, bf16 MFMA internal.
// Pipeline: weight transpose/cvt -> QKV GEMMs -> flash attn (no barriers) -> out GEMM.

typedef __bf16 bf16;
typedef __bf16 bf16x4 __attribute__((ext_vector_type(4)));
typedef __bf16 bf16x8 __attribute__((ext_vector_type(8)));
typedef float f32x4 __attribute__((ext_vector_type(4)));

#define MFMA16(a, b, c) __builtin_amdgcn_mfma_f32_16x16x32_bf16((a), (b), (c), 0, 0, 0)

__device__ inline float exp2_hw(float x) {
    float r; asm("v_exp_f32 %0, %1" : "=v"(r) : "v"(x)); return r;   // 2^x
}

// ---------------------------------------------------------------------------
// Weight transpose + f32->bf16: WT[n][k] = (bf16)W[k][n], 1024x1024 each.
// Grid (16,16,4); z selects the weight. Scalar LDS writes/reads (2-way max).
// ---------------------------------------------------------------------------
__global__ __launch_bounds__(256) void transpose_cvt_kernel(
    const float* __restrict__ W0, const float* __restrict__ W1,
    const float* __restrict__ W2, const float* __restrict__ W3,
    bf16* __restrict__ T0, bf16* __restrict__ T1,
    bf16* __restrict__ T2, bf16* __restrict__ T3)
{
    __shared__ float Ls[64][65];
    const float* W; bf16* T;
    switch (blockIdx.z) {
        case 0:  W = W0; T = T0; break;
        case 1:  W = W1; T = T1; break;
        case 2:  W = W2; T = T2; break;
        default: W = W3; T = T3; break;
    }
    const int t = threadIdx.x;
    const int n0 = blockIdx.x * 64, k0 = blockIdx.y * 64;
    const int g = t >> 4, c = (t & 15) * 4;

    #pragma unroll
    for (int p = 0; p < 4; ++p) {
        const int row = p * 16 + g;                       // k-row within tile
        float4 f = *(const float4*)&W[(size_t)(k0 + row) * 1024 + n0 + c];
        Ls[row][c + 0] = f.x; Ls[row][c + 1] = f.y;
        Ls[row][c + 2] = f.z; Ls[row][c + 3] = f.w;
    }
    __syncthreads();
    #pragma unroll
    for (int p = 0; p < 4; ++p) {
        const int n = p * 16 + g;                         // n-row of WT
        bf16x4 h;
        h[0] = (bf16)Ls[c + 0][n]; h[1] = (bf16)Ls[c + 1][n];
        h[2] = (bf16)Ls[c + 2][n]; h[3] = (bf16)Ls[c + 3][n];
        *(bf16x4*)&T[(size_t)(n0 + n) * 1024 + k0 + c] = h;
    }
}

// ---------------------------------------------------------------------------
// GEMM: out = (A[M,1024] @ W + bias) * alpha, W given as WT[n][k] bf16.
// BM=128, BN=64, BK=64; grid (16,32) -> 512 blocks (2/CU). 4 waves, 64x32 each.
// mode 0: out[m][n]; mode 1: per-batch transposed out[b][n][t], m=b*2048+t.
// ---------------------------------------------------------------------------
template <typename TA, typename TO>
__global__ __launch_bounds__(256) void gemm_kernel(
    const TA* __restrict__ A, const bf16* __restrict__ WT,
    const float* __restrict__ bias, TO* __restrict__ out,
    float alpha, int mode)
{
    __shared__ bf16 As[128][72];
    __shared__ bf16 Bs[64][72];

    // XCD-aware swizzle (nwg=512, %8==0 -> bijective)
    const int fid = blockIdx.x + (blockIdx.y << 4);
    const int swz = (fid & 7) * 64 + (fid >> 3);
    const int n0 = (swz & 15) * 64;
    const int m0 = (swz >> 4) * 128;

    const int tid = threadIdx.x;
    const int w = tid >> 6, lane = tid & 63;
    const int lr = lane & 15, lg = lane >> 4;
    const int wm = (w >> 1) * 64, wn = (w & 1) * 32;

    f32x4 acc[4][2] = {};

    #pragma unroll 1
    for (int kt = 0; kt < 1024; kt += 64) {
        if constexpr (std::is_same<TA, float>::value) {
            #pragma unroll
            for (int p = 0; p < 8; ++p) {
                int c = p * 256 + tid;                    // 2048 float4 chunks
                int row = c >> 4, c4 = (c & 15) * 4;
                float4 f = *(const float4*)&A[(size_t)(m0 + row) * 1024 + kt + c4];
                bf16x4 h;
                h[0] = (bf16)f.x; h[1] = (bf16)f.y; h[2] = (bf16)f.z; h[3] = (bf16)f.w;
                *(bf16x4*)&As[row][c4] = h;
            }
        } else {
            #pragma unroll
            for (int p = 0; p < 4; ++p) {
                int c = p * 256 + tid;                    // 1024 bf16x8 chunks
                int row = c >> 3, c8 = (c & 7) * 8;
                *(uint4*)&As[row][c8] = *(const uint4*)&A[(size_t)(m0 + row) * 1024 + kt + c8];
            }
        }
        #pragma unroll
        for (int p = 0; p < 2; ++p) {
            int c = p * 256 + tid;                        // 512 bf16x8 chunks
            int row = c >> 3, c8 = (c & 7) * 8;
            *(uint4*)&Bs[row][c8] = *(const uint4*)&WT[(size_t)(n0 + row) * 1024 + kt + c8];
        }
        __syncthreads();

        #pragma unroll
        for (int ks = 0; ks < 2; ++ks) {
            const int kb = ks * 32 + lg * 8;
            bf16x8 af[4], bfv[2];
            #pragma unroll
            for (int mt = 0; mt < 4; ++mt)
                af[mt] = *(const bf16x8*)&As[wm + mt * 16 + lr][kb];
            #pragma unroll
            for (int nt = 0; nt < 2; ++nt)
                bfv[nt] = *(const bf16x8*)&Bs[wn + nt * 16 + lr][kb];
            #pragma unroll
            for (int nt = 0; nt < 2; ++nt)
                #pragma unroll
                for (int mt = 0; mt < 4; ++mt)
                    acc[mt][nt] = MFMA16(af[mt], bfv[nt], acc[mt][nt]);
        }
        __syncthreads();
    }

    #pragma unroll
    for (int nt = 0; nt < 2; ++nt) {
        const int n = n0 + wn + nt * 16 + lr;
        const float bv = bias[n];
        #pragma unroll
        for (int mt = 0; mt < 4; ++mt) {
            #pragma unroll
            for (int i = 0; i < 4; ++i) {
                const int m = m0 + wm + mt * 16 + lg * 4 + i;
                const float v = (acc[mt][nt][i] + bv) * alpha;
                if (mode == 0) {
                    out[(size_t)m * 1024 + n] = (TO)v;
                } else {
                    const int b = m >> 11, t = m & 2047;
                    out[((size_t)(b << 10) + n) * 2048 + t] = (TO)v;
                }
            }
        }
    }
}

// ---------------------------------------------------------------------------
// Flash attention, log2-domain softmax (logits pre-scaled by log2e).
// Grid (32,16,2), 256 thr = 4 independent waves (no barriers), 16 q-rows each.
// Pipeline: V(t) loads at top; QK^T; prefetch K(t+1); softmax; PV.
// ---------------------------------------------------------------------------
__global__ __launch_bounds__(256) void attn_kernel(
    const bf16* __restrict__ Q, const bf16* __restrict__ K,
    const bf16* __restrict__ Vt, const float* __restrict__ mbias,
    bf16* __restrict__ Oout)
{
    __shared__ bf16 Ps[4][16][72];   // per-wave private

    const int tid = threadIdx.x;
    const int w = tid >> 6, lane = tid & 63;
    const int lr = lane & 15, lg = lane >> 4;

    // XCD swizzle (nwg=1024): one XCD holds 4 (h,b) groups x all 32 q-tiles
    const int fid = blockIdx.x + (blockIdx.y << 5) + (blockIdx.z << 9);
    const int swz = (fid & 7) * 128 + (fid >> 3);
    const int qt = swz & 31, h = (swz >> 5) & 15, b = swz >> 9;
    const int qrow = qt * 64 + w * 16;

    const size_t qoff = (size_t)(b * 2048 + qrow + lr) * 1024 + h * 64;
    bf16x8 qf[2];
    qf[0] = *(const bf16x8*)&Q[qoff + lg * 8];
    qf[1] = *(const bf16x8*)&Q[qoff + 32 + lg * 8];

    const bf16* Kb = K + (size_t)b * 2048 * 1024 + h * 64;
    const bf16* Vb = Vt + ((size_t)b * 1024 + h * 64) * 2048;
    const float* biasb = mbias + b * 2048;

    float m_run[4], l_run[4];
    f32x4 of[4] = {};
    #pragma unroll
    for (int i = 0; i < 4; ++i) { m_run[i] = -INFINITY; l_run[i] = 0.f; }

    // preload K tile 0 fragments
    bf16x8 kf[2][4];
    #pragma unroll
    for (int ks = 0; ks < 2; ++ks)
        #pragma unroll
        for (int nt = 0; nt < 4; ++nt)
            kf[ks][nt] = *(const bf16x8*)&Kb[(size_t)(nt * 16 + lr) * 1024 + ks * 32 + lg * 8];

    #pragma unroll 1
    for (int key0 = 0; key0 < 2048; key0 += 64) {
        // ---- V(t) fragment loads issued first (hide under QK+softmax) ----
        bf16x8 vf[2][4];
        #pragma unroll
        for (int ks = 0; ks < 2; ++ks)
            #pragma unroll
            for (int dt = 0; dt < 4; ++dt)
                vf[ks][dt] = *(const bf16x8*)&Vb[(size_t)(dt * 16 + lr) * 2048 + key0 + ks * 32 + lg * 8];

        float bvv[4];
        #pragma unroll
        for (int nt = 0; nt < 4; ++nt)
            bvv[nt] = biasb[key0 + nt * 16 + lr] * 1.44269504f;

        // ---- S = Q K^T ----
        f32x4 s[4] = {};
        __builtin_amdgcn_s_setprio(1);
        #pragma unroll
        for (int ks = 0; ks < 2; ++ks)
            #pragma unroll
            for (int nt = 0; nt < 4; ++nt)
                s[nt] = MFMA16(qf[ks], kf[ks][nt], s[nt]);
        __builtin_amdgcn_s_setprio(0);

        // ---- prefetch K(t+1) (wraps harmlessly on last tile) ----
        const int kn = (key0 + 64) & 2047;
        #pragma unroll
        for (int ks = 0; ks < 2; ++ks)
            #pragma unroll
            for (int nt = 0; nt < 4; ++nt)
                kf[ks][nt] = *(const bf16x8*)&Kb[(size_t)(kn + nt * 16 + lr) * 1024 + ks * 32 + lg * 8];

        // ---- softmax (log2 domain) ----
        float rowm[4] = {-INFINITY, -INFINITY, -INFINITY, -INFINITY};
        #pragma unroll
        for (int nt = 0; nt < 4; ++nt)
            #pragma unroll
            for (int i = 0; i < 4; ++i) {
                s[nt][i] += bvv[nt];
                rowm[i] = fmaxf(rowm[i], s[nt][i]);
            }
        #pragma unroll
        for (int off = 1; off < 16; off <<= 1)
            #pragma unroll
            for (int i = 0; i < 4; ++i)
                rowm[i] = fmaxf(rowm[i], __shfl_xor(rowm[i], off, 64));

        float al[4];
        #pragma unroll
        for (int i = 0; i < 4; ++i) {
            const float mnew = fmaxf(m_run[i], rowm[i]);
            al[i] = exp2_hw(m_run[i] - mnew);
            m_run[i] = mnew;
            l_run[i] *= al[i];
            #pragma unroll
            for (int dt = 0; dt < 4; ++dt) of[dt][i] *= al[i];
        }
        float rsum[4] = {0.f, 0.f, 0.f, 0.f};
        #pragma unroll
        for (int nt = 0; nt < 4; ++nt)
            #pragma unroll
            for (int i = 0; i < 4; ++i) {
                const float p = exp2_hw(s[nt][i] - m_run[i]);
                rsum[i] += p;
                Ps[w][lg * 4 + i][nt * 16 + lr] = (bf16)p;
            }
        #pragma unroll
        for (int off = 1; off < 16; off <<= 1)
            #pragma unroll
            for (int i = 0; i < 4; ++i)
                rsum[i] += __shfl_xor(rsum[i], off, 64);
        #pragma unroll
        for (int i = 0; i < 4; ++i) l_run[i] += rsum[i];

        // ---- O += P V ----
        bf16x8 pa0 = *(const bf16x8*)&Ps[w][lr][lg * 8];
        bf16x8 pa1 = *(const bf16x8*)&Ps[w][lr][32 + lg * 8];
        __builtin_amdgcn_s_setprio(1);
        #pragma unroll
        for (int dt = 0; dt < 4; ++dt) of[dt] = MFMA16(pa0, vf[0][dt], of[dt]);
        #pragma unroll
        for (int dt = 0; dt < 4; ++dt) of[dt] = MFMA16(pa1, vf[1][dt], of[dt]);
        __builtin_amdgcn_s_setprio(0);
    }

    const size_t obase = (size_t)(b * 2048 + qrow + lg * 4) * 1024 + h * 64;
    #pragma unroll
    for (int dt = 0; dt < 4; ++dt)
        #pragma unroll
        for (int i = 0; i < 4; ++i) {
            const float v = of[dt][i] / l_run[i];
            Oout[obase + (size_t)i * 1024 + dt * 16 + lr] = (bf16)v;
        }
}

// ---------------------------------------------------------------------------
extern "C" void kernel_launch(void* const* d_in, const int* in_sizes, int n_in,
                              void* d_out, int out_size, void* d_ws, size_t ws_size,
                              hipStream_t stream) {
    const float* query  = (const float*)d_in[0];
    const float* memory = (const float*)d_in[1];
    const float* mbias  = (const float*)d_in[2];
    const float* Wq = (const float*)d_in[3];
    const float* bq = (const float*)d_in[4];
    const float* Wk = (const float*)d_in[5];
    const float* bk = (const float*)d_in[6];
    const float* Wv = (const float*)d_in[7];
    const float* bv = (const float*)d_in[8];
    const float* Wo = (const float*)d_in[9];
    const float* bo = (const float*)d_in[10];
    float* out = (float*)d_out;

    // ws: 4 x 8MiB activations + 4 x 2MiB transposed weights = 40 MiB
    const size_t SZ = 4096ull * 1024ull * sizeof(bf16);
    const size_t WZ = 1024ull * 1024ull * sizeof(bf16);
    char* ws = (char*)d_ws;
    bf16* Qp  = (bf16*)(ws);
    bf16* Kp  = (bf16*)(ws + SZ);
    bf16* Vtp = (bf16*)(ws + 2 * SZ);
    bf16* Ap  = (bf16*)(ws + 3 * SZ);
    bf16* WTq = (bf16*)(ws + 4 * SZ);
    bf16* WTk = (bf16*)(ws + 4 * SZ + WZ);
    bf16* WTv = (bf16*)(ws + 4 * SZ + 2 * WZ);
    bf16* WTo = (bf16*)(ws + 4 * SZ + 3 * WZ);

    dim3 blk(256);
    transpose_cvt_kernel<<<dim3(16, 16, 4), blk, 0, stream>>>(
        Wq, Wk, Wv, Wo, WTq, WTk, WTv, WTo);

    dim3 gg(16, 32);   // N/64, M/128
    // Q scaled by DH^-0.5 * log2(e) so softmax can run in exp2 domain.
    gemm_kernel<float, bf16><<<gg, blk, 0, stream>>>(query,  WTq, bq, Qp,  0.18033688f, 0);
    gemm_kernel<float, bf16><<<gg, blk, 0, stream>>>(memory, WTk, bk, Kp,  1.0f, 0);
    gemm_kernel<float, bf16><<<gg, blk, 0, stream>>>(memory, WTv, bv, Vtp, 1.0f, 1);
    attn_kernel<<<dim3(32, 16, 2), blk, 0, stream>>>(Qp, Kp, Vtp, mbias, Ap);
    gemm_kernel<bf16, float><<<gg, blk, 0, stream>>>(Ap, WTo, bo, out, 1.0f, 0);
}

// Round 5
// 241.260 us; speedup vs baseline: 1.7347x; 1.4698x over previous
//
#include <hip/hip_runtime.h>
#include <hip/hip_bf16.h>
#include <math.h>
#include <type_traits>

// B=2, LQ=LM=2048, D=1024, H=16, DH=64. f32 I/O, bf16 MFMA internal.
// weight transpose/cvt -> QKV GEMMs -> flash attn (fat waves, no reductions) -> out GEMM.

typedef __bf16 bf16;
typedef __bf16 bf16x4 __attribute__((ext_vector_type(4)));
typedef __bf16 bf16x8 __attribute__((ext_vector_type(8)));
typedef float f32x4 __attribute__((ext_vector_type(4)));

#define MFMA16(a, b, c) __builtin_amdgcn_mfma_f32_16x16x32_bf16((a), (b), (c), 0, 0, 0)

__device__ inline float exp2_hw(float x) {
    float r; asm("v_exp_f32 %0, %1" : "=v"(r) : "v"(x)); return r;   // 2^x
}

// ---------------------------------------------------------------------------
// Weight transpose + f32->bf16: WT[n][k] = (bf16)W[k][n], 1024x1024 each.
// ---------------------------------------------------------------------------
__global__ __launch_bounds__(256) void transpose_cvt_kernel(
    const float* __restrict__ W0, const float* __restrict__ W1,
    const float* __restrict__ W2, const float* __restrict__ W3,
    bf16* __restrict__ T0, bf16* __restrict__ T1,
    bf16* __restrict__ T2, bf16* __restrict__ T3)
{
    __shared__ float Ls[64][65];
    const float* W; bf16* T;
    switch (blockIdx.z) {
        case 0:  W = W0; T = T0; break;
        case 1:  W = W1; T = T1; break;
        case 2:  W = W2; T = T2; break;
        default: W = W3; T = T3; break;
    }
    const int t = threadIdx.x;
    const int n0 = blockIdx.x * 64, k0 = blockIdx.y * 64;
    const int g = t >> 4, c = (t & 15) * 4;

    #pragma unroll
    for (int p = 0; p < 4; ++p) {
        const int row = p * 16 + g;
        float4 f = *(const float4*)&W[(size_t)(k0 + row) * 1024 + n0 + c];
        Ls[row][c + 0] = f.x; Ls[row][c + 1] = f.y;
        Ls[row][c + 2] = f.z; Ls[row][c + 3] = f.w;
    }
    __syncthreads();
    #pragma unroll
    for (int p = 0; p < 4; ++p) {
        const int n = p * 16 + g;
        bf16x4 h;
        h[0] = (bf16)Ls[c + 0][n]; h[1] = (bf16)Ls[c + 1][n];
        h[2] = (bf16)Ls[c + 2][n]; h[3] = (bf16)Ls[c + 3][n];
        *(bf16x4*)&T[(size_t)(n0 + n) * 1024 + k0 + c] = h;
    }
}

// ---------------------------------------------------------------------------
// GEMM: out = (A[M,1024] @ W + bias) * alpha, W given as WT[n][k] bf16.
// BM=128, BN=64, BK=64; grid (16,32). mode 1: V^T layout out[b][n][t].
// ---------------------------------------------------------------------------
template <typename TA, typename TO>
__global__ __launch_bounds__(256) void gemm_kernel(
    const TA* __restrict__ A, const bf16* __restrict__ WT,
    const float* __restrict__ bias, TO* __restrict__ out,
    float alpha, int mode)
{
    __shared__ bf16 As[128][72];
    __shared__ bf16 Bs[64][72];

    const int fid = blockIdx.x + (blockIdx.y << 4);
    const int swz = (fid & 7) * 64 + (fid >> 3);
    const int n0 = (swz & 15) * 64;
    const int m0 = (swz >> 4) * 128;

    const int tid = threadIdx.x;
    const int w = tid >> 6, lane = tid & 63;
    const int lr = lane & 15, lg = lane >> 4;
    const int wm = (w >> 1) * 64, wn = (w & 1) * 32;

    f32x4 acc[4][2] = {};

    #pragma unroll 1
    for (int kt = 0; kt < 1024; kt += 64) {
        if constexpr (std::is_same<TA, float>::value) {
            #pragma unroll
            for (int p = 0; p < 8; ++p) {
                int c = p * 256 + tid;
                int row = c >> 4, c4 = (c & 15) * 4;
                float4 f = *(const float4*)&A[(size_t)(m0 + row) * 1024 + kt + c4];
                bf16x4 h;
                h[0] = (bf16)f.x; h[1] = (bf16)f.y; h[2] = (bf16)f.z; h[3] = (bf16)f.w;
                *(bf16x4*)&As[row][c4] = h;
            }
        } else {
            #pragma unroll
            for (int p = 0; p < 4; ++p) {
                int c = p * 256 + tid;
                int row = c >> 3, c8 = (c & 7) * 8;
                *(uint4*)&As[row][c8] = *(const uint4*)&A[(size_t)(m0 + row) * 1024 + kt + c8];
            }
        }
        #pragma unroll
        for (int p = 0; p < 2; ++p) {
            int c = p * 256 + tid;
            int row = c >> 3, c8 = (c & 7) * 8;
            *(uint4*)&Bs[row][c8] = *(const uint4*)&WT[(size_t)(n0 + row) * 1024 + kt + c8];
        }
        __syncthreads();

        #pragma unroll
        for (int ks = 0; ks < 2; ++ks) {
            const int kb = ks * 32 + lg * 8;
            bf16x8 af[4], bfv[2];
            #pragma unroll
            for (int mt = 0; mt < 4; ++mt)
                af[mt] = *(const bf16x8*)&As[wm + mt * 16 + lr][kb];
            #pragma unroll
            for (int nt = 0; nt < 2; ++nt)
                bfv[nt] = *(const bf16x8*)&Bs[wn + nt * 16 + lr][kb];
            #pragma unroll
            for (int nt = 0; nt < 2; ++nt)
                #pragma unroll
                for (int mt = 0; mt < 4; ++mt)
                    acc[mt][nt] = MFMA16(af[mt], bfv[nt], acc[mt][nt]);
        }
        __syncthreads();
    }

    #pragma unroll
    for (int nt = 0; nt < 2; ++nt) {
        const int n = n0 + wn + nt * 16 + lr;
        const float bv = bias[n];
        #pragma unroll
        for (int mt = 0; mt < 4; ++mt) {
            #pragma unroll
            for (int i = 0; i < 4; ++i) {
                const int m = m0 + wm + mt * 16 + lg * 4 + i;
                const float v = (acc[mt][nt][i] + bv) * alpha;
                if (mode == 0) {
                    out[(size_t)m * 1024 + n] = (TO)v;
                } else {
                    const int b = m >> 11, t = m & 2047;
                    out[((size_t)(b << 10) + n) * 2048 + t] = (TO)v;
                }
            }
        }
    }
}

// ---------------------------------------------------------------------------
// Flash attention v2. Grid (16,16,2) = 512 blocks, 4 waves x 32 q-rows each.
// Per key-tile (64 keys): QK^T (2 m-frags) -> defer-max softmax (no cross-lane
// reduce in common path) -> P->LDS -> PV MFMA; l accumulated via ones-column
// MFMA (every lane ends with its rows' sums). log2-domain exp.
// ---------------------------------------------------------------------------
__global__ __launch_bounds__(256) void attn_kernel(
    const bf16* __restrict__ Q, const bf16* __restrict__ K,
    const bf16* __restrict__ Vt, const float* __restrict__ mbias,
    bf16* __restrict__ Oout)
{
    __shared__ bf16 Ps[4][32][76];   // stride 38 dwords: b16-store banks fully spread

    const int tid = threadIdx.x;
    const int w = tid >> 6, lane = tid & 63;
    const int lr = lane & 15, lg = lane >> 4;

    // XCD swizzle (512 blocks): chunk of 64 = 4 (h,b) groups x 16 qt -> 2MB/XCD
    const int fid = blockIdx.x + (blockIdx.y << 4) + (blockIdx.z << 8);
    const int swz = (fid & 7) * 64 + (fid >> 3);
    const int qt = swz & 15, h = (swz >> 4) & 15, b = swz >> 8;
    const int qrow = qt * 128 + w * 32;

    // Q fragments for both m-frags
    bf16x8 qf[2][2];
    #pragma unroll
    for (int mf = 0; mf < 2; ++mf) {
        const size_t qo = (size_t)(b * 2048 + qrow + mf * 16 + lr) * 1024 + h * 64;
        qf[mf][0] = *(const bf16x8*)&Q[qo + lg * 8];
        qf[mf][1] = *(const bf16x8*)&Q[qo + 32 + lg * 8];
    }

    const bf16* kp = K + (size_t)b * 2048 * 1024 + h * 64 + (size_t)lr * 1024 + lg * 8;
    const bf16* vp = Vt + ((size_t)b * 1024 + h * 64 + lr) * 2048 + lg * 8;
    const float* bp = mbias + b * 2048 + lr;

    float m_run[2][4];
    f32x4 of[2][4] = {};
    f32x4 ofl[2] = {};
    #pragma unroll
    for (int mf = 0; mf < 2; ++mf)
        #pragma unroll
        for (int i = 0; i < 4; ++i) m_run[mf][i] = -INFINITY;

    bf16x8 ones8;
    #pragma unroll
    for (int j = 0; j < 8; ++j) ones8[j] = (bf16)1.0f;

    // preload K tile 0 + bias tile 0 (bias pre-scaled to log2 domain)
    bf16x8 kf[2][4];
    #pragma unroll
    for (int ks = 0; ks < 2; ++ks)
        #pragma unroll
        for (int nt = 0; nt < 4; ++nt)
            kf[ks][nt] = *(const bf16x8*)&kp[(size_t)nt * 16384 + ks * 32];
    float bvv[4];
    #pragma unroll
    for (int nt = 0; nt < 4; ++nt) bvv[nt] = bp[nt * 16] * 1.44269504f;

    #pragma unroll 1
    for (int it = 0; it < 32; ++it) {
        // ---- V(t) loads first (consumed at the bottom) ----
        bf16x8 vf[2][4];
        #pragma unroll
        for (int ks = 0; ks < 2; ++ks)
            #pragma unroll
            for (int dt = 0; dt < 4; ++dt)
                vf[ks][dt] = *(const bf16x8*)&vp[(size_t)dt * 32768 + ks * 32];

        // ---- S = Q K^T (both m-frags share kf) ----
        f32x4 s[2][4] = {};
        __builtin_amdgcn_s_setprio(1);
        #pragma unroll
        for (int ks = 0; ks < 2; ++ks)
            #pragma unroll
            for (int nt = 0; nt < 4; ++nt) {
                s[0][nt] = MFMA16(qf[0][ks], kf[ks][nt], s[0][nt]);
                s[1][nt] = MFMA16(qf[1][ks], kf[ks][nt], s[1][nt]);
            }
        __builtin_amdgcn_s_setprio(0);

        // ---- prefetch K(t+1) (last-iter overrun stays inside workspace) ----
        kp += 65536;
        #pragma unroll
        for (int ks = 0; ks < 2; ++ks)
            #pragma unroll
            for (int nt = 0; nt < 4; ++nt)
                kf[ks][nt] = *(const bf16x8*)&kp[(size_t)nt * 16384 + ks * 32];

        // ---- bias add + in-lane row max; defer-max check (no reduce) ----
        float rml[2][4];
        #pragma unroll
        for (int mf = 0; mf < 2; ++mf)
            #pragma unroll
            for (int i = 0; i < 4; ++i) {
                float a0 = s[mf][0][i] + bvv[0], a1 = s[mf][1][i] + bvv[1];
                float a2 = s[mf][2][i] + bvv[2], a3 = s[mf][3][i] + bvv[3];
                s[mf][0][i] = a0; s[mf][1][i] = a1; s[mf][2][i] = a2; s[mf][3][i] = a3;
                rml[mf][i] = fmaxf(fmaxf(a0, a1), fmaxf(a2, a3));
            }
        bool need = false;
        #pragma unroll
        for (int mf = 0; mf < 2; ++mf)
            #pragma unroll
            for (int i = 0; i < 4; ++i)
                need = need || (rml[mf][i] > m_run[mf][i] + 8.f);

        if (__any(need)) {        // rare: full reduce + rescale
            #pragma unroll
            for (int off = 1; off < 16; off <<= 1)
                #pragma unroll
                for (int mf = 0; mf < 2; ++mf)
                    #pragma unroll
                    for (int i = 0; i < 4; ++i)
                        rml[mf][i] = fmaxf(rml[mf][i], __shfl_xor(rml[mf][i], off, 64));
            #pragma unroll
            for (int mf = 0; mf < 2; ++mf)
                #pragma unroll
                for (int i = 0; i < 4; ++i) {
                    const float mnew = fmaxf(m_run[mf][i], rml[mf][i]);
                    const float al = exp2_hw(m_run[mf][i] - mnew);
                    m_run[mf][i] = mnew;
                    ofl[mf][i] *= al;
                    #pragma unroll
                    for (int dt = 0; dt < 4; ++dt) of[mf][dt][i] *= al;
                }
        }

        // ---- prefetch bias(t+1) (guarded: input buffer ends exactly) ----
        bp += (it < 31) ? 64 : 0;
        #pragma unroll
        for (int nt = 0; nt < 4; ++nt) bvv[nt] = bp[nt * 16] * 1.44269504f;

        // ---- P = exp2(S - m), store to wave-private LDS ----
        #pragma unroll
        for (int mf = 0; mf < 2; ++mf)
            #pragma unroll
            for (int nt = 0; nt < 4; ++nt)
                #pragma unroll
                for (int i = 0; i < 4; ++i) {
                    const float p = exp2_hw(s[mf][nt][i] - m_run[mf][i]);
                    Ps[w][mf * 16 + lg * 4 + i][nt * 16 + lr] = (bf16)p;
                }

        // ---- O += P V ; l += P * ones (per-lane row sums via MFMA) ----
        bf16x8 pa[2][2];
        #pragma unroll
        for (int mf = 0; mf < 2; ++mf)
            #pragma unroll
            for (int ks = 0; ks < 2; ++ks)
                pa[mf][ks] = *(const bf16x8*)&Ps[w][mf * 16 + lr][ks * 32 + lg * 8];

        __builtin_amdgcn_s_setprio(1);
        #pragma unroll
        for (int mf = 0; mf < 2; ++mf)
            #pragma unroll
            for (int ks = 0; ks < 2; ++ks) {
                #pragma unroll
                for (int dt = 0; dt < 4; ++dt)
                    of[mf][dt] = MFMA16(pa[mf][ks], vf[ks][dt], of[mf][dt]);
                ofl[mf] = MFMA16(pa[mf][ks], ones8, ofl[mf]);
            }
        __builtin_amdgcn_s_setprio(0);

        vp += 64;
    }

    // ---- finalize: O / l ----
    #pragma unroll
    for (int mf = 0; mf < 2; ++mf) {
        const size_t ob = (size_t)(b * 2048 + qrow + mf * 16 + lg * 4) * 1024 + h * 64;
        #pragma unroll
        for (int i = 0; i < 4; ++i) {
            const float inv = 1.0f / ofl[mf][i];
            #pragma unroll
            for (int dt = 0; dt < 4; ++dt)
                Oout[ob + (size_t)i * 1024 + dt * 16 + lr] = (bf16)(of[mf][dt][i] * inv);
        }
    }
}

// ---------------------------------------------------------------------------
extern "C" void kernel_launch(void* const* d_in, const int* in_sizes, int n_in,
                              void* d_out, int out_size, void* d_ws, size_t ws_size,
                              hipStream_t stream) {
    const float* query  = (const float*)d_in[0];
    const float* memory = (const float*)d_in[1];
    const float* mbias  = (const float*)d_in[2];
    const float* Wq = (const float*)d_in[3];
    const float* bq = (const float*)d_in[4];
    const float* Wk = (const float*)d_in[5];
    const float* bk = (const float*)d_in[6];
    const float* Wv = (const float*)d_in[7];
    const float* bv = (const float*)d_in[8];
    const float* Wo = (const float*)d_in[9];
    const float* bo = (const float*)d_in[10];
    float* out = (float*)d_out;

    const size_t SZ = 4096ull * 1024ull * sizeof(bf16);   // 8 MiB
    const size_t WZ = 1024ull * 1024ull * sizeof(bf16);   // 2 MiB
    char* ws = (char*)d_ws;
    bf16* Qp  = (bf16*)(ws);
    bf16* Kp  = (bf16*)(ws + SZ);
    bf16* Vtp = (bf16*)(ws + 2 * SZ);
    bf16* Ap  = (bf16*)(ws + 3 * SZ);
    bf16* WTq = (bf16*)(ws + 4 * SZ);
    bf16* WTk = (bf16*)(ws + 4 * SZ + WZ);
    bf16* WTv = (bf16*)(ws + 4 * SZ + 2 * WZ);
    bf16* WTo = (bf16*)(ws + 4 * SZ + 3 * WZ);

    dim3 blk(256);
    transpose_cvt_kernel<<<dim3(16, 16, 4), blk, 0, stream>>>(
        Wq, Wk, Wv, Wo, WTq, WTk, WTv, WTo);

    dim3 gg(16, 32);
    // Q scaled by DH^-0.5 * log2(e): softmax runs in exp2 domain.
    gemm_kernel<float, bf16><<<gg, blk, 0, stream>>>(query,  WTq, bq, Qp,  0.18033688f, 0);
    gemm_kernel<float, bf16><<<gg, blk, 0, stream>>>(memory, WTk, bk, Kp,  1.0f, 0);
    gemm_kernel<float, bf16><<<gg, blk, 0, stream>>>(memory, WTv, bv, Vtp, 1.0f, 1);
    attn_kernel<<<dim3(16, 16, 2), blk, 0, stream>>>(Qp, Kp, Vtp, mbias, Ap);
    gemm_kernel<bf16, float><<<gg, blk, 0, stream>>>(Ap, WTo, bo, out, 1.0f, 0);
}